// Round 7
// baseline (417.883 us; speedup 1.0000x reference)
//
#include <hip/hip_runtime.h>
#include <hip/hip_bf16.h>
#include <math.h>

// BezierDeformableAttention on MI355X (gfx950).
// Shapes: B=4 N=900 D=256 C=256 H=W=200, HEADS=8 PTS=4 K=10, hd=32.
// I/O dtype: float32. Internals: bf16 MFMA, f32 accumulate.
//
// R12: measurement round. R7/R8/R9/R11 falsified barrier-style, pipeline
// depth, bank conflicts, and occupancy for the v-GEMM (all ~96 us, 2.5 TB/s,
// 8% MFMA). The unmeasured quantity is the PURE load ceiling of the bev
// access pattern (256 rows x 512 B per block, 160 KB row stride).
//  - probe_loads (runs FIRST): exact bev addresses, no barriers/LDS/stores,
//    asm-sunk, 2 passes (pass1 cold HBM, pass2 L3-warm). Its duration =
//    dur_us(R12) - dur_us(R11) + warm-saving of gemm_v.
//  - side effect: bev is L3-resident when gemm_v runs -> second readout:
//    does a warm source speed gemm_v up (memory-source-bound) or not
//    (interaction-bound)?
//  - production: R9 gemm_v config for ALL z (best known, all variants equal).

typedef unsigned short u16;
typedef unsigned int u32;
typedef short bf16x8 __attribute__((ext_vector_type(8)));
typedef float f32x4 __attribute__((ext_vector_type(4)));

__device__ __forceinline__ float bflo(u32 w) {  // low bf16 of packed word
  union { u32 i; float f; } c; c.i = w << 16; return c.f;
}
__device__ __forceinline__ float bfhi(u32 w) {  // high bf16 of packed word
  union { u32 i; float f; } c; c.i = w & 0xffff0000u; return c.f;
}
__device__ __forceinline__ u16 f2bf(float f) {  // RNE
  union { float f; u32 i; } c; c.f = f;
  u32 u = c.i;
  return (u16)((u + 0x7FFFu + ((u >> 16) & 1u)) >> 16);
}
__device__ __forceinline__ int imin(int a, int b) { return a < b ? a : b; }
__device__ __forceinline__ int imax(int a, int b) { return a > b ? a : b; }

__device__ __forceinline__ void glds16(const u16* g, u16* l) {
  __builtin_amdgcn_global_load_lds(
      (__attribute__((address_space(1))) const void*)g,
      (__attribute__((address_space(3))) void*)l, 16, 0, 0);
}

// ---------------------------------------------------------------- probe
// Exact bev load pattern of gemm_v, free-running (no barriers, no LDS, no
// stores). 2 passes: pass1 = cold HBM ceiling of the pattern, pass2 = L3.
__global__ __launch_bounds__(256) void probe_loads(
    const float* __restrict__ bev)
{
  const int tid = threadIdx.x;
  const int kp = tid >> 4, nb = tid & 15;
  const int n0 = blockIdx.x * 128, z = blockIdx.y;
  const int cb = imin(n0 + nb * 8, 40000 - 8);
  const float* src = bev + ((size_t)z * 256 + 2 * kp) * 40000 + cb;
  float a0 = 0.f, a1 = 0.f, a2 = 0.f, a3 = 0.f;
#pragma unroll
  for (int p = 0; p < 2; ++p) {
#pragma unroll
    for (int s = 0; s < 8; ++s) {
      const float* s2 = src + (size_t)(s * 32) * 40000;
      float4 r0 = *(const float4*)(s2);
      float4 r1 = *(const float4*)(s2 + 4);
      float4 r2 = *(const float4*)(s2 + 40000);
      float4 r3 = *(const float4*)(s2 + 40004);
      a0 += r0.x + r0.y + r0.z + r0.w;
      a1 += r1.x + r1.y + r1.z + r1.w;
      a2 += r2.x + r2.y + r2.z + r2.w;
      a3 += r3.x + r3.y + r3.z + r3.w;
    }
  }
  float v = a0 + a1 + a2 + a3;
  asm volatile("" :: "v"(v));  // keep loads live, no store
}

// ------------------------------------------------ weights prep + q conversion
__global__ __launch_bounds__(256) void prep_weights(
    const float* __restrict__ Wq, const float* __restrict__ Wv,
    const float* __restrict__ Woff, const float* __restrict__ Wattn,
    const float* __restrict__ Wmo, const float* __restrict__ Wo,
    const float* __restrict__ bq, const float* __restrict__ boff,
    const float* __restrict__ battn, const float* __restrict__ bmo,
    const float* __restrict__ bo, const float* __restrict__ query,
    u16* __restrict__ bqoaT, u16* __restrict__ wvT, u16* __restrict__ woCat,
    float* __restrict__ bcat, float* __restrict__ bprime,
    u16* __restrict__ qin)
{
  const int idx = blockIdx.x * 256 + threadIdx.x;
  { // query f32 -> bf16, 921600 elems = 230400 threads x 4
    int i = idx * 4;
    float4 v = *(const float4*)(query + i);
    uint2 st;
    st.x = (u32)f2bf(v.x) | ((u32)f2bf(v.y) << 16);
    st.y = (u32)f2bf(v.z) | ((u32)f2bf(v.w) << 16);
    *(uint2*)(qin + i) = st;
  }
  if (idx < 65536) {
    int r = idx >> 8, c = idx & 255;  // out[r][c] = in[c][r]
    bqoaT[idx] = f2bf(Wq[c * 256 + r]);
    wvT[idx]   = f2bf(Wv[c * 256 + r]);
  }
  if (idx < 24576) {  // (Wq@Woa)^T : n = idx>>8 in [0,96), k = idx&255
    int n = idx >> 8, k = idx & 255;
    const float* wq = Wq + k * 256;
    float s = 0.f;
    if (n < 64) {
      const float* wo = Woff + n;
#pragma unroll 4
      for (int c = 0; c < 256; c += 4) {
        float4 a = *(const float4*)(wq + c);
        s += a.x * wo[(c + 0) * 64] + a.y * wo[(c + 1) * 64] +
             a.z * wo[(c + 2) * 64] + a.w * wo[(c + 3) * 64];
      }
    } else {
      const float* wa = Wattn + (n - 64);
#pragma unroll 4
      for (int c = 0; c < 256; c += 4) {
        float4 a = *(const float4*)(wq + c);
        s += a.x * wa[(c + 0) * 32] + a.y * wa[(c + 1) * 32] +
             a.z * wa[(c + 2) * 32] + a.w * wa[(c + 3) * 32];
      }
    }
    bqoaT[65536 + idx] = f2bf(s);
  }
  if (idx < 131072) {  // woCat[n][k]
    int n = idx >> 9, k = idx & 511;
    float s;
    if (k >= 256) {
      s = Wo[(size_t)(k - 256) * 256 + n];
    } else {
      const float* wm = Wmo + k * 256;
      const float* wo = Wo + n;
      s = 0.f;
#pragma unroll 4
      for (int c = 0; c < 256; c += 4) {
        float4 a = *(const float4*)(wm + c);
        s += a.x * wo[(c + 0) * 256] + a.y * wo[(c + 1) * 256] +
             a.z * wo[(c + 2) * 256] + a.w * wo[(c + 3) * 256];
      }
    }
    woCat[idx] = f2bf(s);
  }
  if (idx >= 131072 && idx < 131328) {  // bprime = bmo@Wo + bo
    int n = idx - 131072;
    const float* wo = Wo + n;
    float s = bo[n];
    for (int c = 0; c < 256; ++c) s += bmo[c] * wo[c * 256];
    bprime[n] = s;
  }
  if (idx >= 131328 && idx < 131680) {  // bcat = [bq | bq@Woa + boa]
    int n = idx - 131328;
    if (n < 256) {
      bcat[n] = bq[n];
    } else {
      int j = n - 256;
      float s;
      if (j < 64) {
        const float* wo = Woff + j;
        s = boff[j];
        for (int c = 0; c < 256; ++c) s += bq[c] * wo[c * 64];
      } else {
        const float* wa = Wattn + (j - 64);
        s = battn[j - 64];
        for (int c = 0; c < 256; ++c) s += bq[c] * wa[c * 32];
      }
      bcat[n] = s;
    }
  }
}

// ---------------------------------------------------------------- MFMA GEMM
enum { GM_F32 = 0, GM_SPLIT = 1 };

template <int MODE>
__global__ __launch_bounds__(256) void gemm_bt(
    const u16* __restrict__ A, const u16* __restrict__ Bt,
    const float* __restrict__ bias,
    u16* __restrict__ outb, float* __restrict__ outf,
    int M, int N, int K, int lda, int ldo)
{
  __shared__ __align__(16) u16 lA[128 * 32];
  __shared__ __align__(16) u16 lB[128 * 32];
  const int tid = threadIdx.x;
  const int wv = tid >> 6, lane = tid & 63;
  const int m0 = blockIdx.y * 128;
  const int n0 = blockIdx.x * 128;

  const int crow = lane >> 2;
  const int ckoff = (lane & 3) * 8;
  const int a1 = imin(m0 + wv * 16 + crow, M - 1);
  const int a2 = imin(m0 + (wv + 4) * 16 + crow, M - 1);
  const int b1 = imin(n0 + wv * 16 + crow, N - 1);
  const int b2 = imin(n0 + (wv + 4) * 16 + crow, N - 1);
  const u16* gA1 = A + (size_t)a1 * lda + ckoff;
  const u16* gA2 = A + (size_t)a2 * lda + ckoff;
  const u16* gB1 = Bt + (size_t)b1 * K + ckoff;
  const u16* gB2 = Bt + (size_t)b2 * K + ckoff;
  u16* lA1 = lA + wv * 512;  u16* lA2 = lA + (wv + 4) * 512;
  u16* lB1 = lB + wv * 512;  u16* lB2 = lB + (wv + 4) * 512;

  const int fm = (wv & 1) * 64, fn = (wv >> 1) * 64;
  const int fr = lane & 15, fk = (lane >> 4) * 8;

  f32x4 acc[4][4];
#pragma unroll
  for (int i = 0; i < 4; ++i)
#pragma unroll
    for (int j = 0; j < 4; ++j) acc[i][j] = (f32x4){0.f, 0.f, 0.f, 0.f};

  for (int k0 = 0; k0 < K; k0 += 32) {
    glds16(gA1 + k0, lA1);
    glds16(gA2 + k0, lA2);
    glds16(gB1 + k0, lB1);
    glds16(gB2 + k0, lB2);
    __syncthreads();
    bf16x8 af[4], bfv[4];
#pragma unroll
    for (int i = 0; i < 4; ++i)
      af[i] = *(const bf16x8*)&lA[(fm + i * 16 + fr) * 32 + fk];
#pragma unroll
    for (int j = 0; j < 4; ++j)
      bfv[j] = *(const bf16x8*)&lB[(fn + j * 16 + fr) * 32 + fk];
    __syncthreads();
#pragma unroll
    for (int i = 0; i < 4; ++i)
#pragma unroll
      for (int j = 0; j < 4; ++j)
        acc[i][j] = __builtin_amdgcn_mfma_f32_16x16x32_bf16(af[i], bfv[j], acc[i][j], 0, 0, 0);
  }

  // epilogue: C/D layout col=lane&15, row=(lane>>4)*4+reg  [measured m89/m91]
  const int quad = lane >> 4;
#pragma unroll
  for (int j = 0; j < 4; ++j) {
    const int n = n0 + fn + j * 16 + fr;
    const bool nok = (n < N);
    const float bcol = bias[nok ? n : 0];
#pragma unroll
    for (int i = 0; i < 4; ++i) {
      const int mb = m0 + fm + i * 16 + quad * 4;
#pragma unroll
      for (int r = 0; r < 4; ++r) {
        const int m = mb + r;
        if (m < M && nok) {
          float x = acc[i][j][r] + bcol;
          if (MODE == GM_F32) {
            outf[(size_t)m * ldo + n] = x;
          } else {  // GM_SPLIT: n<256 -> bf16 @ stride 512, else f32 @ stride 96
            if (n < 256) outb[(size_t)m * 512 + n] = f2bf(x);
            else outf[(size_t)m * 96 + (n - 256)] = x;
          }
        }
      }
    }
  }
}

// ------------------------------------------- fused transpose + v projection
#define LOADB(S, R0, R1, R2, R3)                                   \
  { const float* s2_ = src + (size_t)((S) * 32) * 40000;           \
    R0 = *(const float4*)(s2_);                                    \
    R1 = *(const float4*)(s2_ + 4);                                \
    R2 = *(const float4*)(s2_ + 40000);                            \
    R3 = *(const float4*)(s2_ + 40004); }

#define CVW8(BUF, R0, R1, R2, R3)                                            \
  { u32* lbw_ = (u32*)(BUF); u32 pk_;                                        \
    asm("v_cvt_pk_bf16_f32 %0, %1, %2" : "=v"(pk_) : "v"(R0.x), "v"(R2.x)); \
    lbw_[(((wrow + 0) * 16 + wslot) ^ wxor)] = pk_;                          \
    asm("v_cvt_pk_bf16_f32 %0, %1, %2" : "=v"(pk_) : "v"(R0.y), "v"(R2.y)); \
    lbw_[(((wrow + 1) * 16 + wslot) ^ wxor)] = pk_;                          \
    asm("v_cvt_pk_bf16_f32 %0, %1, %2" : "=v"(pk_) : "v"(R0.z), "v"(R2.z)); \
    lbw_[(((wrow + 2) * 16 + wslot) ^ wxor)] = pk_;                          \
    asm("v_cvt_pk_bf16_f32 %0, %1, %2" : "=v"(pk_) : "v"(R0.w), "v"(R2.w)); \
    lbw_[(((wrow + 3) * 16 + wslot) ^ wxor)] = pk_;                          \
    asm("v_cvt_pk_bf16_f32 %0, %1, %2" : "=v"(pk_) : "v"(R1.x), "v"(R3.x)); \
    lbw_[(((wrow + 4) * 16 + wslot) ^ wxor)] = pk_;                          \
    asm("v_cvt_pk_bf16_f32 %0, %1, %2" : "=v"(pk_) : "v"(R1.y), "v"(R3.y)); \
    lbw_[(((wrow + 5) * 16 + wslot) ^ wxor)] = pk_;                          \
    asm("v_cvt_pk_bf16_f32 %0, %1, %2" : "=v"(pk_) : "v"(R1.z), "v"(R3.z)); \
    lbw_[(((wrow + 6) * 16 + wslot) ^ wxor)] = pk_;                          \
    asm("v_cvt_pk_bf16_f32 %0, %1, %2" : "=v"(pk_) : "v"(R1.w), "v"(R3.w)); \
    lbw_[(((wrow + 7) * 16 + wslot) ^ wxor)] = pk_; }

// ---- R9 structure: A panel staged once (64 KB), 4 reg sets, 1 barrier/slab.
__global__ __launch_bounds__(256, 2) void gemm_v(
    const u16* __restrict__ A, const float* __restrict__ bev,
    const float* __restrict__ bias, u16* __restrict__ outb, int zbase)
{
  __shared__ __align__(16) u16 lA[8 * 128 * 32];  // 64 KB, slab-major
  __shared__ __align__(16) u16 lB[2][128 * 32];   // 2 x 8 KB double buffer
  const int tid = threadIdx.x;
  const int wv = tid >> 6, lane = tid & 63;
  const int m0 = blockIdx.x * 128;
  const int n0 = blockIdx.y * 128;
  const int z = zbase + blockIdx.z;

  const int crow = lane >> 2, ckoff = (lane & 3) * 8;
  const u16* gA1 = A + (size_t)(m0 + wv * 16 + crow) * 256 + ckoff;
  const u16* gA2 = A + (size_t)(m0 + (wv + 4) * 16 + crow) * 256 + ckoff;
  u16* lA1 = lA + wv * 512;
  u16* lA2 = lA + (wv + 4) * 512;

  const int kp = tid >> 4, nb = tid & 15;
  const int cb = imin(n0 + nb * 8, 40000 - 8);
  const float* src = bev + ((size_t)z * 256 + 2 * kp) * 40000 + cb;
  const int wslot = (((kp >> 2) ^ (nb & 3)) << 2) + (kp & 3);  // phys u32 slot
  const int wxor = ((nb >> 2) & 1) << 4;   // bank-spread involution (u32 idx)
  const int wrow = nb * 8;

  const int fm = (wv & 1) * 64, fn = (wv >> 1) * 64;
  const int fr = lane & 15, fk = (lane >> 4) * 8;

  f32x4 acc[4][4];
#pragma unroll
  for (int i = 0; i < 4; ++i)
#pragma unroll
    for (int j = 0; j < 4; ++j) acc[i][j] = (f32x4){0.f, 0.f, 0.f, 0.f};

  float4 s0a, s0b, s0c, s0d, s1a, s1b, s1c, s1d;
  float4 s2a, s2b, s2c, s2d, s3a, s3b, s3c, s3d;

  LOADB(0, s0a, s0b, s0c, s0d);
#pragma unroll
  for (int s = 0; s < 8; ++s) {
    glds16(gA1 + s * 32, lA1 + s * 4096);
    glds16(gA2 + s * 32, lA2 + s * 4096);
  }
  LOADB(1, s1a, s1b, s1c, s1d);
  LOADB(2, s2a, s2b, s2c, s2d);
  LOADB(3, s3a, s3b, s3c, s3d);
  asm volatile("" ::: "memory");
  CVW8(lB[0], s0a, s0b, s0c, s0d);
  __syncthreads();

#pragma unroll
  for (int t = 0; t < 8; ++t) {
    bf16x8 af[4], bfv[4];
#pragma unroll
    for (int i = 0; i < 4; ++i)
      af[i] = *(const bf16x8*)&lA[t * 4096 + (fm + i * 16 + fr) * 32 + fk];
#pragma unroll
    for (int j = 0; j < 4; ++j) {
      const int n = fn + j * 16 + fr;
      const int pc = (((lane >> 4) ^ ((n >> 3) & 3)) << 3);
      const int ri = (n * 32 + pc) ^ (((n >> 5) & 1) << 5);  // wxor twin (u16)
      bfv[j] = *(const bf16x8*)&lB[t & 1][ri];
    }
    if (t == 0)      { LOADB(4, s0a, s0b, s0c, s0d); }
    else if (t == 1) { LOADB(5, s1a, s1b, s1c, s1d); }
    else if (t == 2) { LOADB(6, s2a, s2b, s2c, s2d); }
    else if (t == 3) { LOADB(7, s3a, s3b, s3c, s3d); }
    if (t == 0)      { CVW8(lB[1], s1a, s1b, s1c, s1d); }
    else if (t == 1) { CVW8(lB[0], s2a, s2b, s2c, s2d); }
    else if (t == 2) { CVW8(lB[1], s3a, s3b, s3c, s3d); }
    else if (t == 3) { CVW8(lB[0], s0a, s0b, s0c, s0d); }
    else if (t == 4) { CVW8(lB[1], s1a, s1b, s1c, s1d); }
    else if (t == 5) { CVW8(lB[0], s2a, s2b, s2c, s2d); }
    else if (t == 6) { CVW8(lB[1], s3a, s3b, s3c, s3d); }
#pragma unroll
    for (int i = 0; i < 4; ++i)
#pragma unroll
      for (int j = 0; j < 4; ++j)
        acc[i][j] = __builtin_amdgcn_mfma_f32_16x16x32_bf16(af[i], bfv[j], acc[i][j], 0, 0, 0);
    if (t < 7) {
      __builtin_amdgcn_sched_barrier(0);
      asm volatile("s_waitcnt lgkmcnt(0)" ::: "memory");
      __builtin_amdgcn_sched_barrier(0);
      __builtin_amdgcn_s_barrier();
      __builtin_amdgcn_sched_barrier(0);
    }
  }

  const int quad = lane >> 4;
#pragma unroll
  for (int j = 0; j < 4; ++j) {
    const int n = n0 + fn + j * 16 + fr;
    if (n < 40000) {
#pragma unroll
      for (int i = 0; i < 4; ++i) {
        const int mb = m0 + fm + i * 16 + quad * 4;
        u16 u0 = f2bf(acc[i][j][0] + bias[mb + 0]);
        u16 u1 = f2bf(acc[i][j][1] + bias[mb + 1]);
        u16 u2 = f2bf(acc[i][j][2] + bias[mb + 2]);
        u16 u3 = f2bf(acc[i][j][3] + bias[mb + 3]);
        size_t off = (size_t)z * (8ull * 40000 * 32) +
                     (size_t)(mb >> 5) * (40000 * 32) + (size_t)n * 32 + (mb & 31);
        uint2 st; st.x = (u32)u0 | ((u32)u1 << 16); st.y = (u32)u2 | ((u32)u3 << 16);
        *(uint2*)(outb + off) = st;
      }
    }
  }
}

// ---------------------------------------------------------------- sampler
__global__ __launch_bounds__(256) void sampler(
    const float* __restrict__ ctrl,  // (3600,4,2) f32
    const float* __restrict__ pc,    // (6,) f32
    const float* __restrict__ oa_,   // (3600,96) f32: [0:64) off, [64:96) attn
    const u16* __restrict__ v,       // (B,8,40000,32) bf16
    u16* __restrict__ attn_out)      // qcat (3600,512) bf16, cols [0,256)
{
  __shared__ int   sX0[4][40], sY0[4][40];
  __shared__ float sWx[4][40], sWy[4][40], sAw[4][40];
  const int w = threadIdx.x >> 6, lane = threadIdx.x & 63;
  const int bh = blockIdx.x & 31;          // (b*8+h)
  const int n = (blockIdx.x >> 5) * 4 + w; // 225*4 = 900
  const int h = bh & 7, b = bh >> 3;
  const int row = b * 900 + n;

  if (lane < 40) {
    const int k = lane >> 2, p = lane & 3;
    const float t = (float)k * (1.0f / 9.0f), u = 1.f - t;
    const float c0 = u * u * u, c1 = 3.f * u * u * t, c2 = 3.f * u * t * t, c3 = t * t * t;
    const float* cp = ctrl + (size_t)row * 8;
    float cx = c0 * cp[0] + c1 * cp[2] + c2 * cp[4] + c3 * cp[6];
    float cy = c0 * cp[1] + c1 * cp[3] + c2 * cp[5] + c3 * cp[7];
    float nx = (cx - pc[0]) / (pc[3] - pc[0]);
    float ny = (cy - pc[1]) / (pc[4] - pc[1]);
    nx = fminf(fmaxf(nx, 0.01f), 0.99f);
    ny = fminf(fmaxf(ny, 0.01f), 0.99f);
    const float* oa = oa_ + (size_t)row * 96;
    float ox = oa[h * 8 + p * 2 + 0], oy = oa[h * 8 + p * 2 + 1];
    float l0 = oa[64 + h * 4 + 0], l1 = oa[64 + h * 4 + 1];
    float l2 = oa[64 + h * 4 + 2], l3 = oa[64 + h * 4 + 3];
    float mx = fmaxf(fmaxf(l0, l1), fmaxf(l2, l3));
    float e0 = __expf(l0 - mx), e1 = __expf(l1 - mx), e2 = __expf(l2 - mx), e3 = __expf(l3 - mx);
    float lp = (p == 0) ? l0 : (p == 1) ? l1 : (p == 2) ? l2 : l3;
    float aw = __expf(lp - mx) / (e0 + e1 + e2 + e3);
    float gx = (nx + ox * (1.f / 200.f)) * 200.f - 0.5f;
    float gy = (ny + oy * (1.f / 200.f)) * 200.f - 0.5f;
    float x0 = floorf(gx), y0 = floorf(gy);
    sX0[w][lane] = (int)x0; sY0[w][lane] = (int)y0;
    sWx[w][lane] = gx - x0; sWy[w][lane] = gy - y0; sAw[w][lane] = aw;
  }
  __syncthreads();

  const int sg = lane >> 3;        // sample group 0..7
  const int ch0 = (lane & 7) * 4;  // 4 channels
  const u16* vb = v + ((size_t)(b * 8 + h)) * (40000 * 32) + ch0;
  float a0 = 0.f, a1 = 0.f, a2 = 0.f, a3 = 0.f;
#pragma unroll
  for (int p = 0; p < 5; ++p) {
    const int s = p * 8 + sg;
    const int x0 = sX0[w][s], y0 = sY0[w][s];
    const float wx = sWx[w][s], wy = sWy[w][s], aw = sAw[w][s];
    const int x1 = x0 + 1, y1 = y0 + 1;
    const int cx0 = imin(imax(x0, 0), 199), cx1 = imin(imax(x1, 0), 199);
    const int cy0 = imin(imax(y0, 0), 199), cy1 = imin(imax(y1, 0), 199);
    const bool vx0 = (u32)x0 < 200u, vx1 = (u32)x1 < 200u;
    const bool vy0 = (u32)y0 < 200u, vy1 = (u32)y1 < 200u;
    const float w00 = (vx0 && vy0) ? aw * (1.f - wx) * (1.f - wy) : 0.f;
    const float w10 = (vx1 && vy0) ? aw * wx * (1.f - wy) : 0.f;
    const float w01 = (vx0 && vy1) ? aw * (1.f - wx) * wy : 0.f;
    const float w11 = (vx1 && vy1) ? aw * wx * wy : 0.f;
    uint2 d00 = *(const uint2*)(vb + (size_t)(cy0 * 200 + cx0) * 32);
    uint2 d10 = *(const uint2*)(vb + (size_t)(cy0 * 200 + cx1) * 32);
    uint2 d01 = *(const uint2*)(vb + (size_t)(cy1 * 200 + cx0) * 32);
    uint2 d11 = *(const uint2*)(vb + (size_t)(cy1 * 200 + cx1) * 32);
    a0 += w00 * bflo(d00.x) + w10 * bflo(d10.x) + w01 * bflo(d01.x) + w11 * bflo(d11.x);
    a1 += w00 * bfhi(d00.x) + w10 * bfhi(d10.x) + w01 * bfhi(d01.x) + w11 * bfhi(d11.x);
    a2 += w00 * bflo(d00.y) + w10 * bflo(d10.y) + w01 * bflo(d01.y) + w11 * bflo(d11.y);
    a3 += w00 * bfhi(d00.y) + w10 * bfhi(d10.y) + w01 * bfhi(d01.y) + w11 * bfhi(d11.y);
  }
#pragma unroll
  for (int off = 8; off < 64; off <<= 1) {
    a0 += __shfl_xor(a0, off);
    a1 += __shfl_xor(a1, off);
    a2 += __shfl_xor(a2, off);
    a3 += __shfl_xor(a3, off);
  }
  if (lane < 8) {
    uint2 st;
    st.x = (u32)f2bf(a0) | ((u32)f2bf(a1) << 16);
    st.y = (u32)f2bf(a2) | ((u32)f2bf(a3) << 16);
    *(uint2*)(attn_out + (size_t)row * 512 + h * 32 + ch0) = st;
  }
}

// ---------------------------------------------------------------- launch
extern "C" void kernel_launch(void* const* d_in, const int* in_sizes, int n_in,
                              void* d_out, int out_size, void* d_ws, size_t ws_size,
                              hipStream_t stream)
{
  const float* query = (const float*)d_in[0];
  const float* ctrl  = (const float*)d_in[1];
  const float* bev   = (const float*)d_in[2];
  // d_in[3] spatial_shapes int32 (=200,200) hardcoded
  const float* pc    = (const float*)d_in[4];
  const float* Wq    = (const float*)d_in[5];  const float* bq    = (const float*)d_in[6];
  const float* Wv    = (const float*)d_in[7];  const float* bv    = (const float*)d_in[8];
  const float* Woff  = (const float*)d_in[9];  const float* boff  = (const float*)d_in[10];
  const float* Wattn = (const float*)d_in[11]; const float* battn = (const float*)d_in[12];
  const float* Wmo   = (const float*)d_in[13]; const float* bmo   = (const float*)d_in[14];
  const float* Wo    = (const float*)d_in[15]; const float* bo    = (const float*)d_in[16];

  char* ws = (char*)d_ws;
  size_t off = 0;
  auto alloc = [&](size_t bytes) -> void* {
    void* p = ws + off; off += (bytes + 255) & ~(size_t)255; return p;
  };
  u16*  v     = (u16*)alloc(4ull * 8 * 40000 * 32 * 2); // 81.92 MB
  u16*  qin   = (u16*)alloc(3600ull * 256 * 2);
  u16*  wvT   = (u16*)alloc(65536 * 2);
  u16*  bqoaT = (u16*)alloc(352 * 256 * 2);
  u16*  woCat = (u16*)alloc(256 * 512 * 2);
  float* bcat = (float*)alloc(352 * 4);
  float* bprime = (float*)alloc(256 * 4);
  float* oaf  = (float*)alloc(3600ull * 96 * 4);
  u16*  qcat  = (u16*)alloc(3600ull * 512 * 2);  // [attn | q_bf16]
  (void)ws_size; (void)in_sizes; (void)n_in; (void)out_size;

  probe_loads<<<dim3(313, 4), 256, 0, stream>>>(bev);
  prep_weights<<<900, 256, 0, stream>>>(Wq, Wv, Woff, Wattn, Wmo, Wo,
                                        bq, boff, battn, bmo, bo, query,
                                        bqoaT, wvT, woCat, bcat, bprime, qin);
  gemm_v<<<dim3(2, 313, 4), 256, 0, stream>>>(wvT, bev, bv, v, 0);
  gemm_bt<GM_SPLIT><<<dim3(3, 29), 256, 0, stream>>>(
      qin, bqoaT, bcat, qcat + 256, oaf, 3600, 352, 256, 256, 0);
  sampler<<<7200, 256, 0, stream>>>(ctrl, pc, oaf, v, qcat);
  gemm_bt<GM_F32><<<dim3(2, 29), 256, 0, stream>>>(
      qcat, woCat, bprime, nullptr, (float*)d_out, 3600, 256, 512, 512, 256);
}

// Round 8
// 386.326 us; speedup vs baseline: 1.0817x; 1.0817x over previous
//
#include <hip/hip_runtime.h>
#include <hip/hip_bf16.h>
#include <math.h>

// BezierDeformableAttention on MI355X (gfx950).
// Shapes: B=4 N=900 D=256 C=256 H=W=200, HEADS=8 PTS=4 K=10, hd=32.
// I/O dtype: float32. Internals: bf16 MFMA, f32 accumulate.
//
// R13: A/B on the v-GEMM. R12 probe proved the bev load pattern alone hits
// ~6.3 TB/s and that L3-warm source does NOT help gemm_v -> the limiter is a
// serial full-latency wait inside each slab: hipcc collapses C-level float4
// register pipelines (R9's 4-set lead compiled to VGPR=96 = no lead), and
// __syncthreads drains vmcnt(0) (gemm_v2). Fix: loads the compiler cannot
// collapse.
//  - gemm_v3 (z 0-1): bev loads via asm volatile global_load_dwordx4 into
//    pinned f32x4 sets; hand-counted s_waitcnt vmcnt(12/8/4/0) before each
//    consume (never a mid-loop full drain until the last set, which is 3
//    slabs old by then); sched_barrier(0) after each wait (rule #18).
//    A panel staged once (64 KB); B dbuf 2x8 KB; 1 barrier/slab.
//  - gemm_v  (z 2-3): R9 kernel unchanged (control).

typedef unsigned short u16;
typedef unsigned int u32;
typedef short bf16x8 __attribute__((ext_vector_type(8)));
typedef float f32x4 __attribute__((ext_vector_type(4)));

__device__ __forceinline__ float bflo(u32 w) {  // low bf16 of packed word
  union { u32 i; float f; } c; c.i = w << 16; return c.f;
}
__device__ __forceinline__ float bfhi(u32 w) {  // high bf16 of packed word
  union { u32 i; float f; } c; c.i = w & 0xffff0000u; return c.f;
}
__device__ __forceinline__ u16 f2bf(float f) {  // RNE
  union { float f; u32 i; } c; c.f = f;
  u32 u = c.i;
  return (u16)((u + 0x7FFFu + ((u >> 16) & 1u)) >> 16);
}
__device__ __forceinline__ int imin(int a, int b) { return a < b ? a : b; }
__device__ __forceinline__ int imax(int a, int b) { return a > b ? a : b; }

__device__ __forceinline__ void glds16(const u16* g, u16* l) {
  __builtin_amdgcn_global_load_lds(
      (__attribute__((address_space(1))) const void*)g,
      (__attribute__((address_space(3))) void*)l, 16, 0, 0);
}

// ------------------------------------------------ weights prep + q conversion
__global__ __launch_bounds__(256) void prep_weights(
    const float* __restrict__ Wq, const float* __restrict__ Wv,
    const float* __restrict__ Woff, const float* __restrict__ Wattn,
    const float* __restrict__ Wmo, const float* __restrict__ Wo,
    const float* __restrict__ bq, const float* __restrict__ boff,
    const float* __restrict__ battn, const float* __restrict__ bmo,
    const float* __restrict__ bo, const float* __restrict__ query,
    u16* __restrict__ bqoaT, u16* __restrict__ wvT, u16* __restrict__ woCat,
    float* __restrict__ bcat, float* __restrict__ bprime,
    u16* __restrict__ qin)
{
  const int idx = blockIdx.x * 256 + threadIdx.x;
  { // query f32 -> bf16, 921600 elems = 230400 threads x 4
    int i = idx * 4;
    float4 v = *(const float4*)(query + i);
    uint2 st;
    st.x = (u32)f2bf(v.x) | ((u32)f2bf(v.y) << 16);
    st.y = (u32)f2bf(v.z) | ((u32)f2bf(v.w) << 16);
    *(uint2*)(qin + i) = st;
  }
  if (idx < 65536) {
    int r = idx >> 8, c = idx & 255;  // out[r][c] = in[c][r]
    bqoaT[idx] = f2bf(Wq[c * 256 + r]);
    wvT[idx]   = f2bf(Wv[c * 256 + r]);
  }
  if (idx < 24576) {  // (Wq@Woa)^T : n = idx>>8 in [0,96), k = idx&255
    int n = idx >> 8, k = idx & 255;
    const float* wq = Wq + k * 256;
    float s = 0.f;
    if (n < 64) {
      const float* wo = Woff + n;
#pragma unroll 4
      for (int c = 0; c < 256; c += 4) {
        float4 a = *(const float4*)(wq + c);
        s += a.x * wo[(c + 0) * 64] + a.y * wo[(c + 1) * 64] +
             a.z * wo[(c + 2) * 64] + a.w * wo[(c + 3) * 64];
      }
    } else {
      const float* wa = Wattn + (n - 64);
#pragma unroll 4
      for (int c = 0; c < 256; c += 4) {
        float4 a = *(const float4*)(wq + c);
        s += a.x * wa[(c + 0) * 32] + a.y * wa[(c + 1) * 32] +
             a.z * wa[(c + 2) * 32] + a.w * wa[(c + 3) * 32];
      }
    }
    bqoaT[65536 + idx] = f2bf(s);
  }
  if (idx < 131072) {  // woCat[n][k]
    int n = idx >> 9, k = idx & 511;
    float s;
    if (k >= 256) {
      s = Wo[(size_t)(k - 256) * 256 + n];
    } else {
      const float* wm = Wmo + k * 256;
      const float* wo = Wo + n;
      s = 0.f;
#pragma unroll 4
      for (int c = 0; c < 256; c += 4) {
        float4 a = *(const float4*)(wm + c);
        s += a.x * wo[(c + 0) * 256] + a.y * wo[(c + 1) * 256] +
             a.z * wo[(c + 2) * 256] + a.w * wo[(c + 3) * 256];
      }
    }
    woCat[idx] = f2bf(s);
  }
  if (idx >= 131072 && idx < 131328) {  // bprime = bmo@Wo + bo
    int n = idx - 131072;
    const float* wo = Wo + n;
    float s = bo[n];
    for (int c = 0; c < 256; ++c) s += bmo[c] * wo[c * 256];
    bprime[n] = s;
  }
  if (idx >= 131328 && idx < 131680) {  // bcat = [bq | bq@Woa + boa]
    int n = idx - 131328;
    if (n < 256) {
      bcat[n] = bq[n];
    } else {
      int j = n - 256;
      float s;
      if (j < 64) {
        const float* wo = Woff + j;
        s = boff[j];
        for (int c = 0; c < 256; ++c) s += bq[c] * wo[c * 64];
      } else {
        const float* wa = Wattn + (j - 64);
        s = battn[j - 64];
        for (int c = 0; c < 256; ++c) s += bq[c] * wa[c * 32];
      }
      bcat[n] = s;
    }
  }
}

// ---------------------------------------------------------------- MFMA GEMM
enum { GM_F32 = 0, GM_SPLIT = 1 };

template <int MODE>
__global__ __launch_bounds__(256) void gemm_bt(
    const u16* __restrict__ A, const u16* __restrict__ Bt,
    const float* __restrict__ bias,
    u16* __restrict__ outb, float* __restrict__ outf,
    int M, int N, int K, int lda, int ldo)
{
  __shared__ __align__(16) u16 lA[128 * 32];
  __shared__ __align__(16) u16 lB[128 * 32];
  const int tid = threadIdx.x;
  const int wv = tid >> 6, lane = tid & 63;
  const int m0 = blockIdx.y * 128;
  const int n0 = blockIdx.x * 128;

  const int crow = lane >> 2;
  const int ckoff = (lane & 3) * 8;
  const int a1 = imin(m0 + wv * 16 + crow, M - 1);
  const int a2 = imin(m0 + (wv + 4) * 16 + crow, M - 1);
  const int b1 = imin(n0 + wv * 16 + crow, N - 1);
  const int b2 = imin(n0 + (wv + 4) * 16 + crow, N - 1);
  const u16* gA1 = A + (size_t)a1 * lda + ckoff;
  const u16* gA2 = A + (size_t)a2 * lda + ckoff;
  const u16* gB1 = Bt + (size_t)b1 * K + ckoff;
  const u16* gB2 = Bt + (size_t)b2 * K + ckoff;
  u16* lA1 = lA + wv * 512;  u16* lA2 = lA + (wv + 4) * 512;
  u16* lB1 = lB + wv * 512;  u16* lB2 = lB + (wv + 4) * 512;

  const int fm = (wv & 1) * 64, fn = (wv >> 1) * 64;
  const int fr = lane & 15, fk = (lane >> 4) * 8;

  f32x4 acc[4][4];
#pragma unroll
  for (int i = 0; i < 4; ++i)
#pragma unroll
    for (int j = 0; j < 4; ++j) acc[i][j] = (f32x4){0.f, 0.f, 0.f, 0.f};

  for (int k0 = 0; k0 < K; k0 += 32) {
    glds16(gA1 + k0, lA1);
    glds16(gA2 + k0, lA2);
    glds16(gB1 + k0, lB1);
    glds16(gB2 + k0, lB2);
    __syncthreads();
    bf16x8 af[4], bfv[4];
#pragma unroll
    for (int i = 0; i < 4; ++i)
      af[i] = *(const bf16x8*)&lA[(fm + i * 16 + fr) * 32 + fk];
#pragma unroll
    for (int j = 0; j < 4; ++j)
      bfv[j] = *(const bf16x8*)&lB[(fn + j * 16 + fr) * 32 + fk];
    __syncthreads();
#pragma unroll
    for (int i = 0; i < 4; ++i)
#pragma unroll
      for (int j = 0; j < 4; ++j)
        acc[i][j] = __builtin_amdgcn_mfma_f32_16x16x32_bf16(af[i], bfv[j], acc[i][j], 0, 0, 0);
  }

  // epilogue: C/D layout col=lane&15, row=(lane>>4)*4+reg  [measured m89/m91]
  const int quad = lane >> 4;
#pragma unroll
  for (int j = 0; j < 4; ++j) {
    const int n = n0 + fn + j * 16 + fr;
    const bool nok = (n < N);
    const float bcol = bias[nok ? n : 0];
#pragma unroll
    for (int i = 0; i < 4; ++i) {
      const int mb = m0 + fm + i * 16 + quad * 4;
#pragma unroll
      for (int r = 0; r < 4; ++r) {
        const int m = mb + r;
        if (m < M && nok) {
          float x = acc[i][j][r] + bcol;
          if (MODE == GM_F32) {
            outf[(size_t)m * ldo + n] = x;
          } else {  // GM_SPLIT: n<256 -> bf16 @ stride 512, else f32 @ stride 96
            if (n < 256) outb[(size_t)m * 512 + n] = f2bf(x);
            else outf[(size_t)m * 96 + (n - 256)] = x;
          }
        }
      }
    }
  }
}

// ------------------------------------------- fused transpose + v projection
#define LOADB(S, R0, R1, R2, R3)                                   \
  { const float* s2_ = src + (size_t)((S) * 32) * 40000;           \
    R0 = *(const float4*)(s2_);                                    \
    R1 = *(const float4*)(s2_ + 4);                                \
    R2 = *(const float4*)(s2_ + 40000);                            \
    R3 = *(const float4*)(s2_ + 40004); }

// asm loads the compiler cannot collapse: issue position = program position.
#define GL4(P, R) asm volatile("global_load_dwordx4 %0, %1, off" \
                               : "=v"(R) : "v"(P))
#define LOADB_A(S, R0, R1, R2, R3)                                 \
  { const float* s2_ = src + (size_t)((S) * 32) * 40000;           \
    GL4(s2_, R0); GL4(s2_ + 4, R1);                                \
    GL4(s2_ + 40000, R2); GL4(s2_ + 40004, R3); }

#define CVW8F(BUF, R0, R1, R2, R3)                                           \
  { u32* lbw_ = (u32*)(BUF); u32 pk_;                                        \
    asm("v_cvt_pk_bf16_f32 %0, %1, %2" : "=v"(pk_) : "v"(R0.x), "v"(R2.x)); \
    lbw_[(((wrow + 0) * 16 + wslot) ^ wxor)] = pk_;                          \
    asm("v_cvt_pk_bf16_f32 %0, %1, %2" : "=v"(pk_) : "v"(R0.y), "v"(R2.y)); \
    lbw_[(((wrow + 1) * 16 + wslot) ^ wxor)] = pk_;                          \
    asm("v_cvt_pk_bf16_f32 %0, %1, %2" : "=v"(pk_) : "v"(R0.z), "v"(R2.z)); \
    lbw_[(((wrow + 2) * 16 + wslot) ^ wxor)] = pk_;                          \
    asm("v_cvt_pk_bf16_f32 %0, %1, %2" : "=v"(pk_) : "v"(R0.w), "v"(R2.w)); \
    lbw_[(((wrow + 3) * 16 + wslot) ^ wxor)] = pk_;                          \
    asm("v_cvt_pk_bf16_f32 %0, %1, %2" : "=v"(pk_) : "v"(R1.x), "v"(R3.x)); \
    lbw_[(((wrow + 4) * 16 + wslot) ^ wxor)] = pk_;                          \
    asm("v_cvt_pk_bf16_f32 %0, %1, %2" : "=v"(pk_) : "v"(R1.y), "v"(R3.y)); \
    lbw_[(((wrow + 5) * 16 + wslot) ^ wxor)] = pk_;                          \
    asm("v_cvt_pk_bf16_f32 %0, %1, %2" : "=v"(pk_) : "v"(R1.z), "v"(R3.z)); \
    lbw_[(((wrow + 6) * 16 + wslot) ^ wxor)] = pk_;                          \
    asm("v_cvt_pk_bf16_f32 %0, %1, %2" : "=v"(pk_) : "v"(R1.w), "v"(R3.w)); \
    lbw_[(((wrow + 7) * 16 + wslot) ^ wxor)] = pk_; }

// ext_vector variant (asm-loaded sets)
#define CVW8V(BUF, R0, R1, R2, R3)                                           \
  { u32* lbw_ = (u32*)(BUF); u32 pk_;                                        \
    asm("v_cvt_pk_bf16_f32 %0, %1, %2" : "=v"(pk_) : "v"(R0[0]), "v"(R2[0]));\
    lbw_[(((wrow + 0) * 16 + wslot) ^ wxor)] = pk_;                          \
    asm("v_cvt_pk_bf16_f32 %0, %1, %2" : "=v"(pk_) : "v"(R0[1]), "v"(R2[1]));\
    lbw_[(((wrow + 1) * 16 + wslot) ^ wxor)] = pk_;                          \
    asm("v_cvt_pk_bf16_f32 %0, %1, %2" : "=v"(pk_) : "v"(R0[2]), "v"(R2[2]));\
    lbw_[(((wrow + 2) * 16 + wslot) ^ wxor)] = pk_;                          \
    asm("v_cvt_pk_bf16_f32 %0, %1, %2" : "=v"(pk_) : "v"(R0[3]), "v"(R2[3]));\
    lbw_[(((wrow + 3) * 16 + wslot) ^ wxor)] = pk_;                          \
    asm("v_cvt_pk_bf16_f32 %0, %1, %2" : "=v"(pk_) : "v"(R1[0]), "v"(R3[0]));\
    lbw_[(((wrow + 4) * 16 + wslot) ^ wxor)] = pk_;                          \
    asm("v_cvt_pk_bf16_f32 %0, %1, %2" : "=v"(pk_) : "v"(R1[1]), "v"(R3[1]));\
    lbw_[(((wrow + 5) * 16 + wslot) ^ wxor)] = pk_;                          \
    asm("v_cvt_pk_bf16_f32 %0, %1, %2" : "=v"(pk_) : "v"(R1[2]), "v"(R3[2]));\
    lbw_[(((wrow + 6) * 16 + wslot) ^ wxor)] = pk_;                          \
    asm("v_cvt_pk_bf16_f32 %0, %1, %2" : "=v"(pk_) : "v"(R1[3]), "v"(R3[3]));\
    lbw_[(((wrow + 7) * 16 + wslot) ^ wxor)] = pk_; }

#define VWAIT(N)                                           \
  asm volatile("s_waitcnt vmcnt(" #N ")" ::: "memory");    \
  __builtin_amdgcn_sched_barrier(0);

// ---- asm-pipelined variant: loads uncollapsible, counted vmcnt waits.
__global__ __launch_bounds__(256, 2) void gemm_v3(
    const u16* __restrict__ A, const float* __restrict__ bev,
    const float* __restrict__ bias, u16* __restrict__ outb, int zbase)
{
  __shared__ __align__(16) u16 lA[8 * 128 * 32];  // 64 KB, slab-major
  __shared__ __align__(16) u16 lB[2][128 * 32];   // 2 x 8 KB double buffer
  const int tid = threadIdx.x;
  const int wv = tid >> 6, lane = tid & 63;
  const int m0 = blockIdx.x * 128;
  const int n0 = blockIdx.y * 128;
  const int z = zbase + blockIdx.z;

  const int crow = lane >> 2, ckoff = (lane & 3) * 8;
  const u16* gA1 = A + (size_t)(m0 + wv * 16 + crow) * 256 + ckoff;
  const u16* gA2 = A + (size_t)(m0 + (wv + 4) * 16 + crow) * 256 + ckoff;
  u16* lA1 = lA + wv * 512;
  u16* lA2 = lA + (wv + 4) * 512;

  const int kp = tid >> 4, nb = tid & 15;
  const int cb = imin(n0 + nb * 8, 40000 - 8);
  const float* src = bev + ((size_t)z * 256 + 2 * kp) * 40000 + cb;
  const int wslot = (((kp >> 2) ^ (nb & 3)) << 2) + (kp & 3);
  const int wxor = ((nb >> 2) & 1) << 4;
  const int wrow = nb * 8;

  const int fm = (wv & 1) * 64, fn = (wv >> 1) * 64;
  const int fr = lane & 15, fk = (lane >> 4) * 8;

  f32x4 acc[4][4];
#pragma unroll
  for (int i = 0; i < 4; ++i)
#pragma unroll
    for (int j = 0; j < 4; ++j) acc[i][j] = (f32x4){0.f, 0.f, 0.f, 0.f};

  f32x4 s0a, s0b, s0c, s0d, s1a, s1b, s1c, s1d;
  f32x4 s2a, s2b, s2c, s2d, s3a, s3b, s3c, s3d;

  // prologue: 16 asm loads (slabs 0..3); wait oldest 4 (12 newer) -> stage
  // slab0 into buf0; A panel glds16; full drain (sets 1..3 + A land).
  LOADB_A(0, s0a, s0b, s0c, s0d);
  LOADB_A(1, s1a, s1b, s1c, s1d);
  LOADB_A(2, s2a, s2b, s2c, s2d);
  LOADB_A(3, s3a, s3b, s3c, s3d);
  VWAIT(12)
  CVW8V(lB[0], s0a, s0b, s0c, s0d);
#pragma unroll
  for (int s = 0; s < 8; ++s) {
    glds16(gA1 + s * 32, lA1 + s * 4096);
    glds16(gA2 + s * 32, lA2 + s * 4096);
  }
  __syncthreads();

#pragma unroll
  for (int t = 0; t < 8; ++t) {
    // issue slab t+4 into set t (set t was consumed at iter t-1 / prologue)
    if (t == 0)      { LOADB_A(4, s0a, s0b, s0c, s0d); }
    else if (t == 1) { LOADB_A(5, s1a, s1b, s1c, s1d); }
    else if (t == 2) { LOADB_A(6, s2a, s2b, s2c, s2d); }
    else if (t == 3) { LOADB_A(7, s3a, s3b, s3c, s3d); }
    bf16x8 af[4], bfv[4];
#pragma unroll
    for (int i = 0; i < 4; ++i)
      af[i] = *(const bf16x8*)&lA[t * 4096 + (fm + i * 16 + fr) * 32 + fk];
#pragma unroll
    for (int j = 0; j < 4; ++j) {
      const int n = fn + j * 16 + fr;
      const int pc = (((lane >> 4) ^ ((n >> 3) & 3)) << 3);
      const int ri = (n * 32 + pc) ^ (((n >> 5) & 1) << 5);
      bfv[j] = *(const bf16x8*)&lB[t & 1][ri];
    }
    // counted waits: consume set (t+1)&3; newer loads = 4*(3-(t-3)) for t>=3
    if (t == 3)      { VWAIT(12) }
    else if (t == 4) { VWAIT(8) }
    else if (t == 5) { VWAIT(4) }
    else if (t == 6) { VWAIT(0) }
    // stage slab t+1 into the other buffer
    if (t == 0)      { CVW8V(lB[1], s1a, s1b, s1c, s1d); }
    else if (t == 1) { CVW8V(lB[0], s2a, s2b, s2c, s2d); }
    else if (t == 2) { CVW8V(lB[1], s3a, s3b, s3c, s3d); }
    else if (t == 3) { CVW8V(lB[0], s0a, s0b, s0c, s0d); }
    else if (t == 4) { CVW8V(lB[1], s1a, s1b, s1c, s1d); }
    else if (t == 5) { CVW8V(lB[0], s2a, s2b, s2c, s2d); }
    else if (t == 6) { CVW8V(lB[1], s3a, s3b, s3c, s3d); }
#pragma unroll
    for (int i = 0; i < 4; ++i)
#pragma unroll
      for (int j = 0; j < 4; ++j)
        acc[i][j] = __builtin_amdgcn_mfma_f32_16x16x32_bf16(af[i], bfv[j], acc[i][j], 0, 0, 0);
    if (t < 7) {
      __builtin_amdgcn_sched_barrier(0);
      asm volatile("s_waitcnt lgkmcnt(0)" ::: "memory");
      __builtin_amdgcn_sched_barrier(0);
      __builtin_amdgcn_s_barrier();
      __builtin_amdgcn_sched_barrier(0);
    }
  }

  const int quad = lane >> 4;
#pragma unroll
  for (int j = 0; j < 4; ++j) {
    const int n = n0 + fn + j * 16 + fr;
    if (n < 40000) {
#pragma unroll
      for (int i = 0; i < 4; ++i) {
        const int mb = m0 + fm + i * 16 + quad * 4;
        u16 u0 = f2bf(acc[i][j][0] + bias[mb + 0]);
        u16 u1 = f2bf(acc[i][j][1] + bias[mb + 1]);
        u16 u2 = f2bf(acc[i][j][2] + bias[mb + 2]);
        u16 u3 = f2bf(acc[i][j][3] + bias[mb + 3]);
        size_t off = (size_t)z * (8ull * 40000 * 32) +
                     (size_t)(mb >> 5) * (40000 * 32) + (size_t)n * 32 + (mb & 31);
        uint2 st; st.x = (u32)u0 | ((u32)u1 << 16); st.y = (u32)u2 | ((u32)u3 << 16);
        *(uint2*)(outb + off) = st;
      }
    }
  }
}

// ---- control (R9 structure): A panel staged once, 4 C-level reg sets.
__global__ __launch_bounds__(256, 2) void gemm_v(
    const u16* __restrict__ A, const float* __restrict__ bev,
    const float* __restrict__ bias, u16* __restrict__ outb, int zbase)
{
  __shared__ __align__(16) u16 lA[8 * 128 * 32];  // 64 KB, slab-major
  __shared__ __align__(16) u16 lB[2][128 * 32];   // 2 x 8 KB double buffer
  const int tid = threadIdx.x;
  const int wv = tid >> 6, lane = tid & 63;
  const int m0 = blockIdx.x * 128;
  const int n0 = blockIdx.y * 128;
  const int z = zbase + blockIdx.z;

  const int crow = lane >> 2, ckoff = (lane & 3) * 8;
  const u16* gA1 = A + (size_t)(m0 + wv * 16 + crow) * 256 + ckoff;
  const u16* gA2 = A + (size_t)(m0 + (wv + 4) * 16 + crow) * 256 + ckoff;
  u16* lA1 = lA + wv * 512;
  u16* lA2 = lA + (wv + 4) * 512;

  const int kp = tid >> 4, nb = tid & 15;
  const int cb = imin(n0 + nb * 8, 40000 - 8);
  const float* src = bev + ((size_t)z * 256 + 2 * kp) * 40000 + cb;
  const int wslot = (((kp >> 2) ^ (nb & 3)) << 2) + (kp & 3);
  const int wxor = ((nb >> 2) & 1) << 4;
  const int wrow = nb * 8;

  const int fm = (wv & 1) * 64, fn = (wv >> 1) * 64;
  const int fr = lane & 15, fk = (lane >> 4) * 8;

  f32x4 acc[4][4];
#pragma unroll
  for (int i = 0; i < 4; ++i)
#pragma unroll
    for (int j = 0; j < 4; ++j) acc[i][j] = (f32x4){0.f, 0.f, 0.f, 0.f};

  float4 s0a, s0b, s0c, s0d, s1a, s1b, s1c, s1d;
  float4 s2a, s2b, s2c, s2d, s3a, s3b, s3c, s3d;

  LOADB(0, s0a, s0b, s0c, s0d);
#pragma unroll
  for (int s = 0; s < 8; ++s) {
    glds16(gA1 + s * 32, lA1 + s * 4096);
    glds16(gA2 + s * 32, lA2 + s * 4096);
  }
  LOADB(1, s1a, s1b, s1c, s1d);
  LOADB(2, s2a, s2b, s2c, s2d);
  LOADB(3, s3a, s3b, s3c, s3d);
  asm volatile("" ::: "memory");
  CVW8F(lB[0], s0a, s0b, s0c, s0d);
  __syncthreads();

#pragma unroll
  for (int t = 0; t < 8; ++t) {
    bf16x8 af[4], bfv[4];
#pragma unroll
    for (int i = 0; i < 4; ++i)
      af[i] = *(const bf16x8*)&lA[t * 4096 + (fm + i * 16 + fr) * 32 + fk];
#pragma unroll
    for (int j = 0; j < 4; ++j) {
      const int n = fn + j * 16 + fr;
      const int pc = (((lane >> 4) ^ ((n >> 3) & 3)) << 3);
      const int ri = (n * 32 + pc) ^ (((n >> 5) & 1) << 5);
      bfv[j] = *(const bf16x8*)&lB[t & 1][ri];
    }
    if (t == 0)      { LOADB(4, s0a, s0b, s0c, s0d); }
    else if (t == 1) { LOADB(5, s1a, s1b, s1c, s1d); }
    else if (t == 2) { LOADB(6, s2a, s2b, s2c, s2d); }
    else if (t == 3) { LOADB(7, s3a, s3b, s3c, s3d); }
    if (t == 0)      { CVW8F(lB[1], s1a, s1b, s1c, s1d); }
    else if (t == 1) { CVW8F(lB[0], s2a, s2b, s2c, s2d); }
    else if (t == 2) { CVW8F(lB[1], s3a, s3b, s3c, s3d); }
    else if (t == 3) { CVW8F(lB[0], s0a, s0b, s0c, s0d); }
    else if (t == 4) { CVW8F(lB[1], s1a, s1b, s1c, s1d); }
    else if (t == 5) { CVW8F(lB[0], s2a, s2b, s2c, s2d); }
    else if (t == 6) { CVW8F(lB[1], s3a, s3b, s3c, s3d); }
#pragma unroll
    for (int i = 0; i < 4; ++i)
#pragma unroll
      for (int j = 0; j < 4; ++j)
        acc[i][j] = __builtin_amdgcn_mfma_f32_16x16x32_bf16(af[i], bfv[j], acc[i][j], 0, 0, 0);
    if (t < 7) {
      __builtin_amdgcn_sched_barrier(0);
      asm volatile("s_waitcnt lgkmcnt(0)" ::: "memory");
      __builtin_amdgcn_sched_barrier(0);
      __builtin_amdgcn_s_barrier();
      __builtin_amdgcn_sched_barrier(0);
    }
  }

  const int quad = lane >> 4;
#pragma unroll
  for (int j = 0; j < 4; ++j) {
    const int n = n0 + fn + j * 16 + fr;
    if (n < 40000) {
#pragma unroll
      for (int i = 0; i < 4; ++i) {
        const int mb = m0 + fm + i * 16 + quad * 4;
        u16 u0 = f2bf(acc[i][j][0] + bias[mb + 0]);
        u16 u1 = f2bf(acc[i][j][1] + bias[mb + 1]);
        u16 u2 = f2bf(acc[i][j][2] + bias[mb + 2]);
        u16 u3 = f2bf(acc[i][j][3] + bias[mb + 3]);
        size_t off = (size_t)z * (8ull * 40000 * 32) +
                     (size_t)(mb >> 5) * (40000 * 32) + (size_t)n * 32 + (mb & 31);
        uint2 st; st.x = (u32)u0 | ((u32)u1 << 16); st.y = (u32)u2 | ((u32)u3 << 16);
        *(uint2*)(outb + off) = st;
      }
    }
  }
}

// ---------------------------------------------------------------- sampler
__global__ __launch_bounds__(256) void sampler(
    const float* __restrict__ ctrl,  // (3600,4,2) f32
    const float* __restrict__ pc,    // (6,) f32
    const float* __restrict__ oa_,   // (3600,96) f32: [0:64) off, [64:96) attn
    const u16* __restrict__ v,       // (B,8,40000,32) bf16
    u16* __restrict__ attn_out)      // qcat (3600,512) bf16, cols [0,256)
{
  __shared__ int   sX0[4][40], sY0[4][40];
  __shared__ float sWx[4][40], sWy[4][40], sAw[4][40];
  const int w = threadIdx.x >> 6, lane = threadIdx.x & 63;
  const int bh = blockIdx.x & 31;          // (b*8+h)
  const int n = (blockIdx.x >> 5) * 4 + w; // 225*4 = 900
  const int h = bh & 7, b = bh >> 3;
  const int row = b * 900 + n;

  if (lane < 40) {
    const int k = lane >> 2, p = lane & 3;
    const float t = (float)k * (1.0f / 9.0f), u = 1.f - t;
    const float c0 = u * u * u, c1 = 3.f * u * u * t, c2 = 3.f * u * t * t, c3 = t * t * t;
    const float* cp = ctrl + (size_t)row * 8;
    float cx = c0 * cp[0] + c1 * cp[2] + c2 * cp[4] + c3 * cp[6];
    float cy = c0 * cp[1] + c1 * cp[3] + c2 * cp[5] + c3 * cp[7];
    float nx = (cx - pc[0]) / (pc[3] - pc[0]);
    float ny = (cy - pc[1]) / (pc[4] - pc[1]);
    nx = fminf(fmaxf(nx, 0.01f), 0.99f);
    ny = fminf(fmaxf(ny, 0.01f), 0.99f);
    const float* oa = oa_ + (size_t)row * 96;
    float ox = oa[h * 8 + p * 2 + 0], oy = oa[h * 8 + p * 2 + 1];
    float l0 = oa[64 + h * 4 + 0], l1 = oa[64 + h * 4 + 1];
    float l2 = oa[64 + h * 4 + 2], l3 = oa[64 + h * 4 + 3];
    float mx = fmaxf(fmaxf(l0, l1), fmaxf(l2, l3));
    float e0 = __expf(l0 - mx), e1 = __expf(l1 - mx), e2 = __expf(l2 - mx), e3 = __expf(l3 - mx);
    float lp = (p == 0) ? l0 : (p == 1) ? l1 : (p == 2) ? l2 : l3;
    float aw = __expf(lp - mx) / (e0 + e1 + e2 + e3);
    float gx = (nx + ox * (1.f / 200.f)) * 200.f - 0.5f;
    float gy = (ny + oy * (1.f / 200.f)) * 200.f - 0.5f;
    float x0 = floorf(gx), y0 = floorf(gy);
    sX0[w][lane] = (int)x0; sY0[w][lane] = (int)y0;
    sWx[w][lane] = gx - x0; sWy[w][lane] = gy - y0; sAw[w][lane] = aw;
  }
  __syncthreads();

  const int sg = lane >> 3;        // sample group 0..7
  const int ch0 = (lane & 7) * 4;  // 4 channels
  const u16* vb = v + ((size_t)(b * 8 + h)) * (40000 * 32) + ch0;
  float a0 = 0.f, a1 = 0.f, a2 = 0.f, a3 = 0.f;
#pragma unroll
  for (int p = 0; p < 5; ++p) {
    const int s = p * 8 + sg;
    const int x0 = sX0[w][s], y0 = sY0[w][s];
    const float wx = sWx[w][s], wy = sWy[w][s], aw = sAw[w][s];
    const int x1 = x0 + 1, y1 = y0 + 1;
    const int cx0 = imin(imax(x0, 0), 199), cx1 = imin(imax(x1, 0), 199);
    const int cy0 = imin(imax(y0, 0), 199), cy1 = imin(imax(y1, 0), 199);
    const bool vx0 = (u32)x0 < 200u, vx1 = (u32)x1 < 200u;
    const bool vy0 = (u32)y0 < 200u, vy1 = (u32)y1 < 200u;
    const float w00 = (vx0 && vy0) ? aw * (1.f - wx) * (1.f - wy) : 0.f;
    const float w10 = (vx1 && vy0) ? aw * wx * (1.f - wy) : 0.f;
    const float w01 = (vx0 && vy1) ? aw * (1.f - wx) * wy : 0.f;
    const float w11 = (vx1 && vy1) ? aw * wx * wy : 0.f;
    uint2 d00 = *(const uint2*)(vb + (size_t)(cy0 * 200 + cx0) * 32);
    uint2 d10 = *(const uint2*)(vb + (size_t)(cy0 * 200 + cx1) * 32);
    uint2 d01 = *(const uint2*)(vb + (size_t)(cy1 * 200 + cx0) * 32);
    uint2 d11 = *(const uint2*)(vb + (size_t)(cy1 * 200 + cx1) * 32);
    a0 += w00 * bflo(d00.x) + w10 * bflo(d10.x) + w01 * bflo(d01.x) + w11 * bflo(d11.x);
    a1 += w00 * bfhi(d00.x) + w10 * bfhi(d10.x) + w01 * bfhi(d01.x) + w11 * bfhi(d11.x);
    a2 += w00 * bflo(d00.y) + w10 * bflo(d10.y) + w01 * bflo(d01.y) + w11 * bflo(d11.y);
    a3 += w00 * bfhi(d00.y) + w10 * bfhi(d10.y) + w01 * bfhi(d01.y) + w11 * bfhi(d11.y);
  }
#pragma unroll
  for (int off = 8; off < 64; off <<= 1) {
    a0 += __shfl_xor(a0, off);
    a1 += __shfl_xor(a1, off);
    a2 += __shfl_xor(a2, off);
    a3 += __shfl_xor(a3, off);
  }
  if (lane < 8) {
    uint2 st;
    st.x = (u32)f2bf(a0) | ((u32)f2bf(a1) << 16);
    st.y = (u32)f2bf(a2) | ((u32)f2bf(a3) << 16);
    *(uint2*)(attn_out + (size_t)row * 512 + h * 32 + ch0) = st;
  }
}

// ---------------------------------------------------------------- launch
extern "C" void kernel_launch(void* const* d_in, const int* in_sizes, int n_in,
                              void* d_out, int out_size, void* d_ws, size_t ws_size,
                              hipStream_t stream)
{
  const float* query = (const float*)d_in[0];
  const float* ctrl  = (const float*)d_in[1];
  const float* bev   = (const float*)d_in[2];
  // d_in[3] spatial_shapes int32 (=200,200) hardcoded
  const float* pc    = (const float*)d_in[4];
  const float* Wq    = (const float*)d_in[5];  const float* bq    = (const float*)d_in[6];
  const float* Wv    = (const float*)d_in[7];  const float* bv    = (const float*)d_in[8];
  const float* Woff  = (const float*)d_in[9];  const float* boff  = (const float*)d_in[10];
  const float* Wattn = (const float*)d_in[11]; const float* battn = (const float*)d_in[12];
  const float* Wmo   = (const float*)d_in[13]; const float* bmo   = (const float*)d_in[14];
  const float* Wo    = (const float*)d_in[15]; const float* bo    = (const float*)d_in[16];

  char* ws = (char*)d_ws;
  size_t off = 0;
  auto alloc = [&](size_t bytes) -> void* {
    void* p = ws + off; off += (bytes + 255) & ~(size_t)255; return p;
  };
  u16*  v     = (u16*)alloc(4ull * 8 * 40000 * 32 * 2); // 81.92 MB
  u16*  qin   = (u16*)alloc(3600ull * 256 * 2);
  u16*  wvT   = (u16*)alloc(65536 * 2);
  u16*  bqoaT = (u16*)alloc(352 * 256 * 2);
  u16*  woCat = (u16*)alloc(256 * 512 * 2);
  float* bcat = (float*)alloc(352 * 4);
  float* bprime = (float*)alloc(256 * 4);
  float* oaf  = (float*)alloc(3600ull * 96 * 4);
  u16*  qcat  = (u16*)alloc(3600ull * 512 * 2);  // [attn | q_bf16]
  (void)ws_size; (void)in_sizes; (void)n_in; (void)out_size;

  prep_weights<<<900, 256, 0, stream>>>(Wq, Wv, Woff, Wattn, Wmo, Wo,
                                        bq, boff, battn, bmo, bo, query,
                                        bqoaT, wvT, woCat, bcat, bprime, qin);
  // A/B: z 0-1 asm-pipelined variant, z 2-3 control (identical work each)
  gemm_v3<<<dim3(2, 313, 2), 256, 0, stream>>>(wvT, bev, bv, v, 0);
  gemm_v<<<dim3(2, 313, 2), 256, 0, stream>>>(wvT, bev, bv, v, 2);
  gemm_bt<GM_SPLIT><<<dim3(3, 29), 256, 0, stream>>>(
      qin, bqoaT, bcat, qcat + 256, oaf, 3600, 352, 256, 256, 0);
  sampler<<<7200, 256, 0, stream>>>(ctrl, pc, oaf, v, qcat);
  gemm_bt<GM_F32><<<dim3(2, 29), 256, 0, stream>>>(
      qcat, woCat, bprime, nullptr, (float*)d_out, 3600, 256, 512, 512, 256);
}